// Round 1
// baseline (667.758 us; speedup 1.0000x reference)
//
#include <hip/hip_runtime.h>
#include <math.h>

// Problem constants
#define NROWS   60000
#define DIM     512
#define HIMG    245          // ceil(sqrt(60000)); 245*245 = 60025
#define P2      60025
#define SP      60026        // cls + 60025 positions
#define SPP     60032        // padded
#define RSCALE  0.04419417382415922f  // 1/sqrt(512)

// K5/K7 tiling
#define CI    28             // i-rows per tile
#define TJ    16             // j-cols per tile
#define DCW   32             // d-channels per chunk
#define NJT   16             // ceil(245/16)
#define NIT   9              // ceil(245/28)
#define NDC   16             // 512/32
#define NBLK  (NJT*NIT*NDC)  // 2304
#define XPAD  33             // xx LDS row stride (floats)

// K1 grid
#define NB1   2048
#define RPB   30             // rows per block (2048*30 >= 60000)

// ws layout (float offsets)
#define OFF_PMAX  0          // 2048
#define OFF_PIDX  2048       // 2048 (int)
#define OFF_QROW  4096       // 512
#define OFF_QVEC  4608       // 512
#define OFF_U     5120       // 512*8
#define OFF_S0    9216       // 8
#define OFF_MAXP  9280       // 8*32
#define OFF_ZP    9536       // 8*32
#define OFF_SRAW  9792       // 8*512
#define OFF_O1    13888      // 512
#define OFF_O2    14400      // 512
#define OFF_SPART 16384                      // 16*8*60032 = 7684096
#define OFF_SCOMB (OFF_SPART + 7684096)      // 8*60032
#define OFF_ATTN  (OFF_SCOMB + 480256)       // 8*60032
#define OFF_SBLK  (OFF_ATTN + 480256)        // 144*8*512 = 589824

// ---------------- K1: a1 = sigmoid(in@w_enc + b), A1 out, per-block argmax partials
__global__ __launch_bounds__(256) void k1(const float* __restrict__ in,
                                          const float* __restrict__ w_enc,
                                          const float* __restrict__ b_enc,
                                          float* __restrict__ A1,
                                          float* __restrict__ pmax, int* __restrict__ pidx){
  int b = blockIdx.x;
  int w = threadIdx.x >> 6, l = threadIdx.x & 63;
  float4 we0 = ((const float4*)w_enc)[l];
  float4 we1 = ((const float4*)w_enc)[64 + l];
  float be = b_enc[0];
  int r0 = b * RPB;
  float bm = -3.0e38f; int bi = 0;
  for (int k = w; k < RPB; k += 4){
    int r = r0 + k;
    if (r < NROWS){
      const float4* rp = (const float4*)(in + (size_t)r * DIM);
      float4 x0 = rp[l], x1 = rp[64 + l];
      float s = x0.x*we0.x + x0.y*we0.y + x0.z*we0.z + x0.w*we0.w
              + x1.x*we1.x + x1.y*we1.y + x1.z*we1.z + x1.w*we1.w;
      #pragma unroll
      for (int d = 32; d; d >>= 1) s += __shfl_xor(s, d);
      if (l == 0){
        float z = s + be;
        A1[r] = 1.f / (1.f + __expf(-z));
        if (z > bm){ bm = z; bi = r; }
      }
    }
  }
  __shared__ float sm[4]; __shared__ int si[4];
  if (l == 0){ sm[w] = bm; si[w] = bi; }
  __syncthreads();
  if (threadIdx.x == 0){
    float m = sm[0]; int i = si[0];
    for (int t2 = 1; t2 < 4; t2++){
      if (sm[t2] > m || (sm[t2] == m && si[t2] < i)){ m = sm[t2]; i = si[t2]; }
    }
    pmax[b] = m; pidx[b] = i;
  }
}

// ---------------- K4a: reduce argmax, copy Q row, qvec = Q@w_q + b_q (16 blocks x 32 outputs)
__global__ __launch_bounds__(256) void k4a(const float* __restrict__ in,
                                           const float* __restrict__ pmax, const int* __restrict__ pidx,
                                           const float* __restrict__ w_q, const float* __restrict__ b_q,
                                           float* __restrict__ qvec, float* __restrict__ qrow){
  __shared__ float qs[512];
  __shared__ float rm[256]; __shared__ int ri[256];
  __shared__ float red[256];
  int t = threadIdx.x;
  float m = -3.0e38f; int mi = 0;
  for (int k = t; k < NB1; k += 256){
    float v = pmax[k]; int id = pidx[k];
    if (v > m || (v == m && id < mi)){ m = v; mi = id; }
  }
  rm[t] = m; ri[t] = mi; __syncthreads();
  for (int s = 128; s; s >>= 1){
    if (t < s){
      if (rm[t+s] > rm[t] || (rm[t+s] == rm[t] && ri[t+s] < ri[t])){ rm[t] = rm[t+s]; ri[t] = ri[t+s]; }
    }
    __syncthreads();
  }
  int idx = ri[0];
  for (int k = t; k < 512; k += 256){
    float v = in[(size_t)idx * DIM + k];
    qs[k] = v;
    qrow[k] = v;   // all blocks write identical values (benign)
  }
  __syncthreads();
  int b = blockIdx.x;
  int oo = t & 31, ks = t >> 5;
  int o = b * 32 + oo;
  float acc = 0.f;
  for (int kk = ks * 64; kk < ks * 64 + 64; kk++) acc += qs[kk] * w_q[(size_t)kk * DIM + o];
  red[t] = acc; __syncthreads();
  if (ks == 0){
    float s = red[oo];
    #pragma unroll
    for (int q2 = 1; q2 < 8; q2++) s += red[oo + 32 * q2];
    qvec[o] = s + b_q[o];
  }
}

// ---------------- K4b: u[d][h] = RSCALE * sum_t w_k[d][h*64+t]*qvec[h*64+t]
__global__ __launch_bounds__(256) void k4b(const float* __restrict__ w_k,
                                           const float* __restrict__ qvec, float* __restrict__ u){
  __shared__ float qs[512];
  int t = threadIdx.x;
  for (int k = t; k < 512; k += 256) qs[k] = qvec[k];
  __syncthreads();
  int b = blockIdx.x;
  int dd = t >> 3, h = t & 7;
  int d = b * 32 + dd;
  const float4* wr = (const float4*)(w_k + (size_t)d * DIM + h * 64);
  float acc = 0.f;
  #pragma unroll
  for (int k = 0; k < 16; k++){
    float4 v = wr[k];
    int base = h * 64 + 4 * k;
    acc += v.x * qs[base] + v.y * qs[base+1] + v.z * qs[base+2] + v.w * qs[base+3];
  }
  u[(size_t)d * 8 + h] = acc * RSCALE;
}

// ---------------- K4c: cls score per head: scores0[h] = sum_d cls[d]*u[d][h] + RS*(b_k_h . qh_h)
__global__ __launch_bounds__(512) void k4c(const float* __restrict__ b_k, const float* __restrict__ qvec,
                                           const float* __restrict__ cls, const float* __restrict__ u,
                                           float* __restrict__ scores0){
  int t = threadIdx.x; int w = t >> 6, l = t & 63;  // wave = head
  float c = b_k[t] * qvec[t];
  #pragma unroll
  for (int d = 32; d; d >>= 1) c += __shfl_xor(c, d);
  float cs = 0.f;
  #pragma unroll
  for (int m = 0; m < 8; m++){
    int d = l + m * 64;
    cs += cls[d] * u[(size_t)d * 8 + w];
  }
  #pragma unroll
  for (int d = 32; d; d >>= 1) cs += __shfl_xor(cs, d);
  if (l == 0) scores0[w] = cs + c * RSCALE;
}

// ---------------- K5: fused xs=relu(in-Q) (+ i_shift write) + depthwise conv + score partials
__global__ __launch_bounds__(512) void k5(const float* __restrict__ in,
                                          const float* __restrict__ qrow,
                                          const float* __restrict__ conv_w, const float* __restrict__ conv_b,
                                          const float* __restrict__ u,
                                          float* __restrict__ xs_out, float* __restrict__ spart){
  // XCD-aware bijective swizzle (2304 % 8 == 0)
  int bid = blockIdx.x;
  int sw = (bid & 7) * (NBLK >> 3) + (bid >> 3);
  int dc = sw / (NJT * NIT);
  int r2 = sw % (NJT * NIT);
  int jt = r2 / NIT, it = r2 % NIT;
  int i0 = it * CI, j0 = jt * TJ;
  int t = threadIdx.x;
  int dl = t & 31, jg = t >> 5;         // 16 jg x 32 dl
  int d = dc * DCW + dl;
  int j = j0 + jg;

  __shared__ float xxb[CI * TJ * XPAD]; // 14784 floats
  __shared__ float uls[DCW * 8];        // 256

  if (t < 256) uls[t] = u[(size_t)dc * 256 + t];

  float Qd = qrow[d];
  float w9[9];
  #pragma unroll
  for (int k = 0; k < 9; k++) w9[k] = conv_w[(size_t)d * 9 + k];
  float cb = conv_b[d];

  const bool jok   = (j < HIMG);
  const bool jm1ok = (j - 1 >= 0) && (j - 1 < HIMG);
  const bool jp1ok = (j + 1 < HIMG);

  auto xsl = [&](int p) -> float {
    int ps = (p >= NROWS) ? p - NROWS : p;
    float v = in[(size_t)ps * DIM + d] - Qd;
    return v > 0.f ? v : 0.f;
  };
  float a0=0,b0=0,c0=0,a1=0,b1=0,c1=0,a2,b2,c2;
  auto load3 = [&](int r, bool wr, float& A, float& B, float& C){
    A = 0.f; B = 0.f; C = 0.f;
    if (r >= 0 && r < HIMG){
      int base = r * HIMG;
      if (jm1ok) A = xsl(base + j - 1);
      if (jok){
        int p = base + j;
        B = xsl(p);
        if (wr && p < NROWS) xs_out[(size_t)p * DIM + d] = B;
      }
      if (jp1ok) C = xsl(base + j + 1);
    }
  };

  load3(i0 - 1, false, a0, b0, c0);
  load3(i0,     true,  a1, b1, c1);
  for (int ci = 0; ci < CI; ci++){
    int i = i0 + ci;
    load3(i + 1, ci < CI - 1, a2, b2, c2);
    float xx = 0.f;
    if (i < HIMG && jok){
      xx = cb + b1
         + w9[0]*a0 + w9[1]*b0 + w9[2]*c0
         + w9[3]*a1 + w9[4]*b1 + w9[5]*c1
         + w9[6]*a2 + w9[7]*b2 + w9[8]*c2;
    }
    xxb[(ci * TJ + jg) * XPAD + dl] = xx;
    a0=a1; b0=b1; c0=c1; a1=a2; b1=b2; c1=c2;
  }
  __syncthreads();

  // phase B: scores[p][h] partial over this 32-d chunk
  float acc[4][8] = {};
  int pt = t >> 2, ks = t & 3;
  if (t < 448){
    #pragma unroll
    for (int dd2 = 0; dd2 < 8; dd2++){
      int dloc = ks * 8 + dd2;
      float4 u0 = *(const float4*)(uls + dloc * 8);
      float4 u1 = *(const float4*)(uls + dloc * 8 + 4);
      #pragma unroll
      for (int pp = 0; pp < 4; pp++){
        float xv = xxb[(pt + 112 * pp) * XPAD + dloc];
        acc[pp][0] += xv * u0.x; acc[pp][1] += xv * u0.y;
        acc[pp][2] += xv * u0.z; acc[pp][3] += xv * u0.w;
        acc[pp][4] += xv * u1.x; acc[pp][5] += xv * u1.y;
        acc[pp][6] += xv * u1.z; acc[pp][7] += xv * u1.w;
      }
    }
  }
  __syncthreads();
  float* scr = xxb; // overlay: [ks][pos][h] = ks*3584 + pos*8 + h  (14336 <= 14784)
  if (t < 448){
    #pragma unroll
    for (int pp = 0; pp < 4; pp++){
      int pos = pt + 112 * pp;
      #pragma unroll
      for (int h = 0; h < 8; h++) scr[ks * 3584 + pos * 8 + h] = acc[pp][h];
    }
  }
  __syncthreads();
  if (t < 448){
    int pos = t;
    int ci = pos >> 4, jg2 = pos & 15;
    int i = i0 + ci, jj = j0 + jg2;
    if (i < HIMG && jj < HIMG){
      int sp = i * HIMG + jj + 1;
      #pragma unroll
      for (int h = 0; h < 8; h++){
        float s = scr[pos*8+h] + scr[3584 + pos*8+h] + scr[7168 + pos*8+h] + scr[10752 + pos*8+h];
        spart[((size_t)(dc * 8 + h)) * SPP + sp] = s;
      }
    }
  }
}

// ---------------- K6a: combine score partials, write scomb, block max partials
__global__ __launch_bounds__(256) void k6a(const float* __restrict__ spart, const float* __restrict__ scores0,
                                           float* __restrict__ scomb, float* __restrict__ maxpart){
  int b = blockIdx.x, t = threadIdx.x;
  int h = b >> 5, sl = b & 31;
  int sp0 = sl * 1876, sp1 = min(sp0 + 1876, SP);
  float m = -3.0e38f;
  for (int sp = sp0 + t; sp < sp1; sp += 256){
    float v;
    if (sp == 0) v = scores0[h];
    else {
      v = 0.f;
      #pragma unroll
      for (int dcc = 0; dcc < NDC; dcc++) v += spart[((size_t)(dcc * 8 + h)) * SPP + sp];
    }
    scomb[(size_t)h * SPP + sp] = v;
    m = fmaxf(m, v);
  }
  __shared__ float red[256];
  red[t] = m; __syncthreads();
  for (int s = 128; s; s >>= 1){ if (t < s) red[t] = fmaxf(red[t], red[t+s]); __syncthreads(); }
  if (t == 0) maxpart[h * 32 + sl] = red[0];
}

// ---------------- K6c: e = exp(s - m), write attn (unnormalized), Z partials
__global__ __launch_bounds__(256) void k6c(const float* __restrict__ scomb, const float* __restrict__ maxpart,
                                           float* __restrict__ attn, float* __restrict__ zpart){
  int b = blockIdx.x, t = threadIdx.x;
  int h = b >> 5, sl = b & 31;
  float m = -3.0e38f;
  #pragma unroll
  for (int k = 0; k < 32; k++) m = fmaxf(m, maxpart[h * 32 + k]);
  int sp0 = sl * 1876, sp1 = min(sp0 + 1876, SP);
  float z = 0.f;
  for (int sp = sp0 + t; sp < sp1; sp += 256){
    float e = __expf(scomb[(size_t)h * SPP + sp] - m);
    attn[(size_t)h * SPP + sp] = e;
    z += e;
  }
  __shared__ float red[256];
  red[t] = z; __syncthreads();
  for (int s = 128; s; s >>= 1){ if (t < s) red[t] += red[t+s]; __syncthreads(); }
  if (t == 0) zpart[h * 32 + sl] = red[0];
}

// ---------------- K7: recompute conv, weighted sums s_blk[h][d] += e*xx
__global__ __launch_bounds__(512) void k7(const float* __restrict__ xs_src,
                                          const float* __restrict__ conv_w, const float* __restrict__ conv_b,
                                          const float* __restrict__ attn, float* __restrict__ sblk){
  int bid = blockIdx.x;
  int sw = (bid & 7) * (NBLK >> 3) + (bid >> 3);
  int dc = sw / (NJT * NIT);
  int r2 = sw % (NJT * NIT);
  int jt = r2 / NIT, it = r2 % NIT;
  int i0 = it * CI, j0 = jt * TJ;
  int t = threadIdx.x;
  int dl = t & 31, jg = t >> 5;
  int d = dc * DCW + dl;
  int j = j0 + jg;

  __shared__ float xxb[CI * TJ * XPAD];
  __shared__ float att[8 * 448];

  // stage attn tile (e-values), transposed to [h][pos]
  if (t < 448){
    int ci = t >> 4, jg2 = t & 15;
    int i = i0 + ci, jj = j0 + jg2;
    bool ok = (i < HIMG) && (jj < HIMG);
    int sp = ok ? (i * HIMG + jj + 1) : 0;
    #pragma unroll
    for (int h = 0; h < 8; h++) att[h * 448 + t] = ok ? attn[(size_t)h * SPP + sp] : 0.f;
  }

  float w9[9];
  #pragma unroll
  for (int k = 0; k < 9; k++) w9[k] = conv_w[(size_t)d * 9 + k];
  float cb = conv_b[d];

  const bool jok   = (j < HIMG);
  const bool jm1ok = (j - 1 >= 0) && (j - 1 < HIMG);
  const bool jp1ok = (j + 1 < HIMG);
  auto xsl = [&](int p) -> float {
    int ps = (p >= NROWS) ? p - NROWS : p;
    return xs_src[(size_t)ps * DIM + d];
  };
  float a0=0,b0=0,c0=0,a1=0,b1=0,c1=0,a2,b2,c2;
  auto load3 = [&](int r, float& A, float& B, float& C){
    A = 0.f; B = 0.f; C = 0.f;
    if (r >= 0 && r < HIMG){
      int base = r * HIMG;
      if (jm1ok) A = xsl(base + j - 1);
      if (jok)   B = xsl(base + j);
      if (jp1ok) C = xsl(base + j + 1);
    }
  };
  load3(i0 - 1, a0, b0, c0);
  load3(i0,     a1, b1, c1);
  for (int ci = 0; ci < CI; ci++){
    int i = i0 + ci;
    load3(i + 1, a2, b2, c2);
    float xx = 0.f;
    if (i < HIMG && jok){
      xx = cb + b1
         + w9[0]*a0 + w9[1]*b0 + w9[2]*c0
         + w9[3]*a1 + w9[4]*b1 + w9[5]*c1
         + w9[6]*a2 + w9[7]*b2 + w9[8]*c2;
    }
    xxb[(ci * TJ + jg) * XPAD + dl] = xx;
    a0=a1; b0=b1; c0=c1; a1=a2; b1=b2; c1=c2;
  }
  __syncthreads();

  // phase B: acc[h][k] = sum over pos-slice of att[h][pos]*xx[pos][dg*4+k]
  float acc[8][4] = {};
  int dg = t & 7, sl = t >> 3;
  if (t < 448){
    #pragma unroll
    for (int pp = 0; pp < 8; pp++){
      int pos = sl + 56 * pp;
      int xb = pos * XPAD + dg * 4;
      float x0 = xxb[xb], x1 = xxb[xb+1], x2 = xxb[xb+2], x3 = xxb[xb+3];
      #pragma unroll
      for (int h = 0; h < 8; h++){
        float av = att[h * 448 + pos];
        acc[h][0] += av * x0; acc[h][1] += av * x1;
        acc[h][2] += av * x2; acc[h][3] += av * x3;
      }
    }
  }
  __syncthreads();
  float* scr = xxb; // overlay: ((sl*8+dg)*8+h)*4+k  -> 14336 floats
  if (t < 448){
    #pragma unroll
    for (int h = 0; h < 8; h++)
      #pragma unroll
      for (int k = 0; k < 4; k++) scr[((sl * 8 + dg) * 8 + h) * 4 + k] = acc[h][k];
  }
  __syncthreads();
  if (t < 256){
    int h = t >> 5, dl2 = t & 31, dg2 = dl2 >> 2, k = dl2 & 3;
    float s = 0.f;
    #pragma unroll 8
    for (int s2 = 0; s2 < 56; s2++) s += scr[((s2 * 8 + dg2) * 8 + h) * 4 + k];
    sblk[((size_t)(jt * NIT + it) * 8 + h) * DIM + dc * DCW + dl2] = s;
  }
}

// ---------------- K7b: reduce sblk over 144 tiles -> sraw[h][d]
__global__ __launch_bounds__(64) void k7b(const float* __restrict__ sblk, float* __restrict__ sraw){
  int b = blockIdx.x;           // 64 = 8 h x 8 dq
  int h = b >> 3, dq = b & 7;
  int d = dq * 64 + threadIdx.x;
  float s = 0.f;
  for (int t2 = 0; t2 < NJT * NIT; t2++) s += sblk[((size_t)t2 * 8 + h) * DIM + d];
  sraw[h * DIM + d] = s;
}

// ---------------- K8a: O1[o] = qvec[o] + b_v[o] + sfin(h). w_v[:,o]
__global__ __launch_bounds__(256) void k8a(const float* __restrict__ sraw, const float* __restrict__ zpart,
                                           const float* __restrict__ attn, const float* __restrict__ cls,
                                           const float* __restrict__ qvec, const float* __restrict__ b_v,
                                           const float* __restrict__ w_v, float* __restrict__ O1){
  int b = blockIdx.x, t = threadIdx.x;
  int h = b >> 1;
  __shared__ float sf[512]; __shared__ float red[256];
  float Zh = 0.f;
  #pragma unroll
  for (int k = 0; k < 32; k++) Zh += zpart[h * 32 + k];
  float e0 = attn[(size_t)h * SPP];
  for (int k = t; k < 512; k += 256) sf[k] = (sraw[h * DIM + k] + e0 * cls[k]) / Zh;
  __syncthreads();
  int oo = t & 31, ks = t >> 5;
  int o = b * 32 + oo;
  float acc = 0.f;
  for (int kk = ks * 64; kk < ks * 64 + 64; kk++) acc += sf[kk] * w_v[(size_t)kk * DIM + o];
  red[t] = acc; __syncthreads();
  if (ks == 0){
    float s = red[oo];
    #pragma unroll
    for (int q2 = 1; q2 < 8; q2++) s += red[oo + 32 * q2];
    O1[o] = qvec[o] + b_v[o] + s;
  }
}

// ---------------- K8b: O2 = O1 + relu(O1@w_o + b_o)
__global__ __launch_bounds__(256) void k8b(const float* __restrict__ O1, const float* __restrict__ w_o,
                                           const float* __restrict__ b_o, float* __restrict__ O2){
  int b = blockIdx.x, t = threadIdx.x;
  __shared__ float sf[512]; __shared__ float red[256];
  for (int k = t; k < 512; k += 256) sf[k] = O1[k];
  __syncthreads();
  int oo = t & 31, ks = t >> 5;
  int o = b * 32 + oo;
  float acc = 0.f;
  for (int kk = ks * 64; kk < ks * 64 + 64; kk++) acc += sf[kk] * w_o[(size_t)kk * DIM + o];
  red[t] = acc; __syncthreads();
  if (ks == 0){
    float s = red[oo];
    #pragma unroll
    for (int q2 = 1; q2 < 8; q2++) s += red[oo + 32 * q2];
    float r = s + b_o[o];
    O2[o] = sf[o] + (r > 0.f ? r : 0.f);
  }
}

// ---------------- K8c: out = O2@w_fc + b_fc (2 logits)
__global__ __launch_bounds__(256) void k8c(const float* __restrict__ O2, const float* __restrict__ w_fc,
                                           const float* __restrict__ b_fc, float* __restrict__ out){
  int t = threadIdx.x;
  __shared__ float r0[256], r1[256];
  float a0 = 0.f, a1 = 0.f;
  for (int k = t; k < 512; k += 256){
    float v = O2[k];
    a0 += v * w_fc[2 * k];
    a1 += v * w_fc[2 * k + 1];
  }
  r0[t] = a0; r1[t] = a1; __syncthreads();
  for (int s = 128; s; s >>= 1){ if (t < s){ r0[t] += r0[t+s]; r1[t] += r1[t+s]; } __syncthreads(); }
  if (t == 0){ out[0] = r0[0] + b_fc[0]; out[1] = r1[0] + b_fc[1]; }
}

extern "C" void kernel_launch(void* const* d_in, const int* in_sizes, int n_in,
                              void* d_out, int out_size, void* d_ws, size_t ws_size,
                              hipStream_t stream) {
  const float* in     = (const float*)d_in[0];
  const float* w_enc  = (const float*)d_in[1];
  const float* b_enc  = (const float*)d_in[2];
  const float* cls    = (const float*)d_in[3];
  const float* conv_w = (const float*)d_in[4];
  const float* conv_b = (const float*)d_in[5];
  const float* w_q    = (const float*)d_in[6];
  const float* b_q    = (const float*)d_in[7];
  const float* w_k    = (const float*)d_in[8];
  const float* b_k    = (const float*)d_in[9];
  const float* w_v    = (const float*)d_in[10];
  const float* b_v    = (const float*)d_in[11];
  const float* w_o    = (const float*)d_in[12];
  const float* b_o    = (const float*)d_in[13];
  const float* w_fc   = (const float*)d_in[14];
  const float* b_fc   = (const float*)d_in[15];

  float* out    = (float*)d_out;
  float* xs_out = out + 2;                      // i_shift (1,60000,512)
  float* A1     = out + 2 + (size_t)NROWS * DIM;
  float* ws     = (float*)d_ws;

  k1 <<<NB1, 256, 0, stream>>>(in, w_enc, b_enc, A1, ws + OFF_PMAX, (int*)(ws + OFF_PIDX));
  k4a<<<16, 256, 0, stream>>>(in, ws + OFF_PMAX, (const int*)(ws + OFF_PIDX), w_q, b_q,
                              ws + OFF_QVEC, ws + OFF_QROW);
  k4b<<<16, 256, 0, stream>>>(w_k, ws + OFF_QVEC, ws + OFF_U);
  k4c<<<1, 512, 0, stream>>>(b_k, ws + OFF_QVEC, cls, ws + OFF_U, ws + OFF_S0);
  k5 <<<NBLK, 512, 0, stream>>>(in, ws + OFF_QROW, conv_w, conv_b, ws + OFF_U,
                                xs_out, ws + OFF_SPART);
  k6a<<<256, 256, 0, stream>>>(ws + OFF_SPART, ws + OFF_S0, ws + OFF_SCOMB, ws + OFF_MAXP);
  k6c<<<256, 256, 0, stream>>>(ws + OFF_SCOMB, ws + OFF_MAXP, ws + OFF_ATTN, ws + OFF_ZP);
  k7 <<<NBLK, 512, 0, stream>>>(xs_out, conv_w, conv_b, ws + OFF_ATTN, ws + OFF_SBLK);
  k7b<<<64, 64, 0, stream>>>(ws + OFF_SBLK, ws + OFF_SRAW);
  k8a<<<16, 256, 0, stream>>>(ws + OFF_SRAW, ws + OFF_ZP, ws + OFF_ATTN, cls,
                              ws + OFF_QVEC, b_v, w_v, ws + OFF_O1);
  k8b<<<16, 256, 0, stream>>>(ws + OFF_O1, w_o, b_o, ws + OFF_O2);
  k8c<<<1, 256, 0, stream>>>(ws + OFF_O2, w_fc, b_fc, out);
}

// Round 2
// 607.265 us; speedup vs baseline: 1.0996x; 1.0996x over previous
//
#include <hip/hip_runtime.h>
#include <math.h>

// Problem constants
#define NROWS   60000
#define DIM     512
#define HIMG    245          // ceil(sqrt(60000)); 245*245 = 60025
#define P2      60025
#define SP      60026        // cls + 60025 positions
#define SPP     60032        // padded
#define RSCALE  0.04419417382415922f  // 1/sqrt(512)

// K5/K7 tiling
#define CI    28             // i-rows per tile
#define CIH   14             // rows per phase-half (K5)
#define TJ    16             // j-cols per tile
#define DCW   32             // d-channels per chunk
#define NJT   16             // ceil(245/16)
#define NIT   9              // ceil(245/28)
#define NDC   16             // 512/32
#define NBLK  (NJT*NIT*NDC)  // 2304
#define XPAD  33             // xx LDS row stride (floats)

// K1 grid
#define NB1   2048
#define RPB   30             // rows per block (2048*30 >= 60000)

// ws layout (float offsets)
#define OFF_PMAX  0          // 2048
#define OFF_PIDX  2048       // 2048 (int)
#define OFF_QROW  4096       // 512
#define OFF_QVEC  4608       // 512
#define OFF_U     5120       // 512*8
#define OFF_S0    9216       // 8
#define OFF_MAXP  9280       // 8*32
#define OFF_ZP    9536       // 8*32
#define OFF_SRAW  9792       // 8*512
#define OFF_O1    13888      // 512
#define OFF_O2    14400      // 512
#define OFF_SPART 16384                      // 16*8*60032 = 7684096
#define OFF_SCOMB (OFF_SPART + 7684096)      // 8*60032
#define OFF_ATTN  (OFF_SCOMB + 480256)       // 8*60032
#define OFF_SBLK  (OFF_ATTN + 480256)        // 144*8*512 = 589824

// ---------------- K1: a1 = sigmoid(in@w_enc + b), A1 out, per-block argmax partials
__global__ __launch_bounds__(256) void k1(const float* __restrict__ in,
                                          const float* __restrict__ w_enc,
                                          const float* __restrict__ b_enc,
                                          float* __restrict__ A1,
                                          float* __restrict__ pmax, int* __restrict__ pidx){
  int b = blockIdx.x;
  int w = threadIdx.x >> 6, l = threadIdx.x & 63;
  float4 we0 = ((const float4*)w_enc)[l];
  float4 we1 = ((const float4*)w_enc)[64 + l];
  float be = b_enc[0];
  int r0 = b * RPB;
  float bm = -3.0e38f; int bi = 0;
  for (int k = w; k < RPB; k += 4){
    int r = r0 + k;
    if (r < NROWS){
      const float4* rp = (const float4*)(in + (size_t)r * DIM);
      float4 x0 = rp[l], x1 = rp[64 + l];
      float s = x0.x*we0.x + x0.y*we0.y + x0.z*we0.z + x0.w*we0.w
              + x1.x*we1.x + x1.y*we1.y + x1.z*we1.z + x1.w*we1.w;
      #pragma unroll
      for (int d = 32; d; d >>= 1) s += __shfl_xor(s, d);
      if (l == 0){
        float z = s + be;
        A1[r] = 1.f / (1.f + __expf(-z));
        if (z > bm){ bm = z; bi = r; }
      }
    }
  }
  __shared__ float sm[4]; __shared__ int si[4];
  if (l == 0){ sm[w] = bm; si[w] = bi; }
  __syncthreads();
  if (threadIdx.x == 0){
    float m = sm[0]; int i = si[0];
    for (int t2 = 1; t2 < 4; t2++){
      if (sm[t2] > m || (sm[t2] == m && si[t2] < i)){ m = sm[t2]; i = si[t2]; }
    }
    pmax[b] = m; pidx[b] = i;
  }
}

// ---------------- K4a: reduce argmax, copy Q row, qvec = Q@w_q + b_q (16 blocks x 32 outputs)
__global__ __launch_bounds__(256) void k4a(const float* __restrict__ in,
                                           const float* __restrict__ pmax, const int* __restrict__ pidx,
                                           const float* __restrict__ w_q, const float* __restrict__ b_q,
                                           float* __restrict__ qvec, float* __restrict__ qrow){
  __shared__ float qs[512];
  __shared__ float rm[256]; __shared__ int ri[256];
  __shared__ float red[256];
  int t = threadIdx.x;
  float m = -3.0e38f; int mi = 0;
  for (int k = t; k < NB1; k += 256){
    float v = pmax[k]; int id = pidx[k];
    if (v > m || (v == m && id < mi)){ m = v; mi = id; }
  }
  rm[t] = m; ri[t] = mi; __syncthreads();
  for (int s = 128; s; s >>= 1){
    if (t < s){
      if (rm[t+s] > rm[t] || (rm[t+s] == rm[t] && ri[t+s] < ri[t])){ rm[t] = rm[t+s]; ri[t] = ri[t+s]; }
    }
    __syncthreads();
  }
  int idx = ri[0];
  for (int k = t; k < 512; k += 256){
    float v = in[(size_t)idx * DIM + k];
    qs[k] = v;
    qrow[k] = v;   // all blocks write identical values (benign)
  }
  __syncthreads();
  int b = blockIdx.x;
  int oo = t & 31, ks = t >> 5;
  int o = b * 32 + oo;
  float acc = 0.f;
  for (int kk = ks * 64; kk < ks * 64 + 64; kk++) acc += qs[kk] * w_q[(size_t)kk * DIM + o];
  red[t] = acc; __syncthreads();
  if (ks == 0){
    float s = red[oo];
    #pragma unroll
    for (int q2 = 1; q2 < 8; q2++) s += red[oo + 32 * q2];
    qvec[o] = s + b_q[o];
  }
}

// ---------------- K4b: u[d][h] = RSCALE * sum_t w_k[d][h*64+t]*qvec[h*64+t]
__global__ __launch_bounds__(256) void k4b(const float* __restrict__ w_k,
                                           const float* __restrict__ qvec, float* __restrict__ u){
  __shared__ float qs[512];
  int t = threadIdx.x;
  for (int k = t; k < 512; k += 256) qs[k] = qvec[k];
  __syncthreads();
  int b = blockIdx.x;
  int dd = t >> 3, h = t & 7;
  int d = b * 32 + dd;
  const float4* wr = (const float4*)(w_k + (size_t)d * DIM + h * 64);
  float acc = 0.f;
  #pragma unroll
  for (int k = 0; k < 16; k++){
    float4 v = wr[k];
    int base = h * 64 + 4 * k;
    acc += v.x * qs[base] + v.y * qs[base+1] + v.z * qs[base+2] + v.w * qs[base+3];
  }
  u[(size_t)d * 8 + h] = acc * RSCALE;
}

// ---------------- K4c: cls score per head
__global__ __launch_bounds__(512) void k4c(const float* __restrict__ b_k, const float* __restrict__ qvec,
                                           const float* __restrict__ cls, const float* __restrict__ u,
                                           float* __restrict__ scores0){
  int t = threadIdx.x; int w = t >> 6, l = t & 63;  // wave = head
  float c = b_k[t] * qvec[t];
  #pragma unroll
  for (int d = 32; d; d >>= 1) c += __shfl_xor(c, d);
  float cs = 0.f;
  #pragma unroll
  for (int m = 0; m < 8; m++){
    int d = l + m * 64;
    cs += cls[d] * u[(size_t)d * 8 + w];
  }
  #pragma unroll
  for (int d = 32; d; d >>= 1) cs += __shfl_xor(cs, d);
  if (l == 0) scores0[w] = cs + c * RSCALE;
}

// ---------------- K5: fused xs=relu(in-Q) (+ i_shift) + depthwise conv + score partials
// Halved xxb tile (14 rows) -> 30.6 KB LDS -> 4 blocks/CU. Phase B reduces over
// the 4 ks-lanes via shfl_xor instead of an LDS overlay (saves 2 barriers/half).
__global__ __launch_bounds__(512, 8) void k5(const float* __restrict__ in,
                                          const float* __restrict__ qrow,
                                          const float* __restrict__ conv_w, const float* __restrict__ conv_b,
                                          const float* __restrict__ u,
                                          float* __restrict__ xs_out, float* __restrict__ spart){
  int bid = blockIdx.x;
  int sw = (bid & 7) * (NBLK >> 3) + (bid >> 3);
  int dc = sw / (NJT * NIT);
  int r2 = sw % (NJT * NIT);
  int jt = r2 / NIT, it = r2 % NIT;
  int i0 = it * CI, j0 = jt * TJ;
  int t = threadIdx.x;
  int dl = t & 31, jg = t >> 5;         // 16 jg x 32 dl
  int d = dc * DCW + dl;
  int j = j0 + jg;

  __shared__ float xxb[CIH * TJ * XPAD]; // 7392 floats
  __shared__ float uls[DCW * 8];         // 256

  if (t < 256) uls[t] = u[(size_t)dc * 256 + t];

  float Qd = qrow[d];
  float w9[9];
  #pragma unroll
  for (int k = 0; k < 9; k++) w9[k] = conv_w[(size_t)d * 9 + k];
  float cb = conv_b[d];

  const bool jok   = (j < HIMG);
  const bool jm1ok = (j - 1 >= 0) && (j - 1 < HIMG);
  const bool jp1ok = (j + 1 < HIMG);

  auto xsl = [&](int p) -> float {
    int ps = (p >= NROWS) ? p - NROWS : p;
    float v = in[(size_t)ps * DIM + d] - Qd;
    return v > 0.f ? v : 0.f;
  };
  float a0=0,b0=0,c0=0,a1=0,b1=0,c1=0,a2,b2,c2;
  auto load3 = [&](int r, bool wr, float& A, float& B, float& C){
    A = 0.f; B = 0.f; C = 0.f;
    if (r >= 0 && r < HIMG){
      int base = r * HIMG;
      if (jm1ok) A = xsl(base + j - 1);
      if (jok){
        int p = base + j;
        B = xsl(p);
        if (wr && p < NROWS) xs_out[(size_t)p * DIM + d] = B;
      }
      if (jp1ok) C = xsl(base + j + 1);
    }
  };

  load3(i0 - 1, false, a0, b0, c0);
  load3(i0,     true,  a1, b1, c1);

  for (int half = 0; half < 2; half++){
    for (int cl = 0; cl < CIH; cl++){
      int ci = half * CIH + cl;
      int i = i0 + ci;
      load3(i + 1, ci < CI - 1, a2, b2, c2);
      float xx = 0.f;
      if (i < HIMG && jok){
        xx = cb + b1
           + w9[0]*a0 + w9[1]*b0 + w9[2]*c0
           + w9[3]*a1 + w9[4]*b1 + w9[5]*c1
           + w9[6]*a2 + w9[7]*b2 + w9[8]*c2;
      }
      xxb[(cl * TJ + jg) * XPAD + dl] = xx;
      a0=a1; b0=b1; c0=c1; a1=a2; b1=b2; c1=c2;
    }
    __syncthreads();

    // phase B: scores for 224 positions of this half
    if (t < 448){
      int pt = t >> 2, ks = t & 3;       // 112 pt x 4 ks (8 d each)
      float acc[2][8] = {};
      #pragma unroll
      for (int dd2 = 0; dd2 < 8; dd2++){
        int dloc = ks * 8 + dd2;
        float4 u0 = *(const float4*)(uls + dloc * 8);
        float4 u1 = *(const float4*)(uls + dloc * 8 + 4);
        #pragma unroll
        for (int pp = 0; pp < 2; pp++){
          float xv = xxb[(pt + 112 * pp) * XPAD + dloc];
          acc[pp][0] += xv * u0.x; acc[pp][1] += xv * u0.y;
          acc[pp][2] += xv * u0.z; acc[pp][3] += xv * u0.w;
          acc[pp][4] += xv * u1.x; acc[pp][5] += xv * u1.y;
          acc[pp][6] += xv * u1.z; acc[pp][7] += xv * u1.w;
        }
      }
      // reduce over ks (lane bits 0-1)
      #pragma unroll
      for (int pp = 0; pp < 2; pp++)
        #pragma unroll
        for (int h = 0; h < 8; h++){
          float v = acc[pp][h];
          v += __shfl_xor(v, 1);
          v += __shfl_xor(v, 2);
          acc[pp][h] = v;
        }
      if (ks == 0){
        #pragma unroll
        for (int pp = 0; pp < 2; pp++){
          int pos = pt + 112 * pp;
          int cl2 = pos >> 4, jg2 = pos & 15;
          int i = i0 + half * CIH + cl2, jj = j0 + jg2;
          if (i < HIMG && jj < HIMG){
            int sp = i * HIMG + jj + 1;
            #pragma unroll
            for (int h = 0; h < 8; h++)
              spart[((size_t)(dc * 8 + h)) * SPP + sp] = acc[pp][h];
          }
        }
      }
    }
    __syncthreads();
  }
}

// ---------------- K6a: combine score partials, write scomb, block max partials
__global__ __launch_bounds__(256) void k6a(const float* __restrict__ spart, const float* __restrict__ scores0,
                                           float* __restrict__ scomb, float* __restrict__ maxpart){
  int b = blockIdx.x, t = threadIdx.x;
  int h = b >> 5, sl = b & 31;
  int sp0 = sl * 1876, sp1 = min(sp0 + 1876, SP);
  float m = -3.0e38f;
  for (int sp = sp0 + t; sp < sp1; sp += 256){
    float v;
    if (sp == 0) v = scores0[h];
    else {
      v = 0.f;
      #pragma unroll
      for (int dcc = 0; dcc < NDC; dcc++) v += spart[((size_t)(dcc * 8 + h)) * SPP + sp];
    }
    scomb[(size_t)h * SPP + sp] = v;
    m = fmaxf(m, v);
  }
  __shared__ float red[256];
  red[t] = m; __syncthreads();
  for (int s = 128; s; s >>= 1){ if (t < s) red[t] = fmaxf(red[t], red[t+s]); __syncthreads(); }
  if (t == 0) maxpart[h * 32 + sl] = red[0];
}

// ---------------- K6c: e = exp(s - m), write attn (unnormalized), Z partials
__global__ __launch_bounds__(256) void k6c(const float* __restrict__ scomb, const float* __restrict__ maxpart,
                                           float* __restrict__ attn, float* __restrict__ zpart){
  int b = blockIdx.x, t = threadIdx.x;
  int h = b >> 5, sl = b & 31;
  float m = -3.0e38f;
  #pragma unroll
  for (int k = 0; k < 32; k++) m = fmaxf(m, maxpart[h * 32 + k]);
  int sp0 = sl * 1876, sp1 = min(sp0 + 1876, SP);
  float z = 0.f;
  for (int sp = sp0 + t; sp < sp1; sp += 256){
    float e = __expf(scomb[(size_t)h * SPP + sp] - m);
    attn[(size_t)h * SPP + sp] = e;
    z += e;
  }
  __shared__ float red[256];
  red[t] = z; __syncthreads();
  for (int s = 128; s; s >>= 1){ if (t < s) red[t] += red[t+s]; __syncthreads(); }
  if (t == 0) zpart[h * 32 + sl] = red[0];
}

// ---------------- K7: recompute conv, weighted sums into registers (no xx LDS)
__global__ __launch_bounds__(512, 8) void k7(const float* __restrict__ xs_src,
                                          const float* __restrict__ conv_w, const float* __restrict__ conv_b,
                                          const float* __restrict__ attn, float* __restrict__ sblk){
  int bid = blockIdx.x;
  int sw = (bid & 7) * (NBLK >> 3) + (bid >> 3);
  int dc = sw / (NJT * NIT);
  int r2 = sw % (NJT * NIT);
  int jt = r2 / NIT, it = r2 % NIT;
  int i0 = it * CI, j0 = jt * TJ;
  int t = threadIdx.x;
  int dl = t & 31, jg = t >> 5;
  int d = dc * DCW + dl;
  int j = j0 + jg;

  __shared__ float smem[448 * 8];   // att [pos][h]; reused as wred [8w][8h][32d]

  // stage attn tile, [pos][h] layout, conflict-free LDS writes
  #pragma unroll
  for (int c = 0; c < 7; c++){
    int idx = c * 512 + t;
    int pos = idx >> 3, h = idx & 7;
    int ci = pos >> 4, jg2 = pos & 15;
    int i = i0 + ci, jj = j0 + jg2;
    bool ok = (i < HIMG) && (jj < HIMG);
    smem[idx] = ok ? attn[(size_t)h * SPP + i * HIMG + jj + 1] : 0.f;
  }

  float w9[9];
  #pragma unroll
  for (int k = 0; k < 9; k++) w9[k] = conv_w[(size_t)d * 9 + k];
  float cb = conv_b[d];

  const bool jok   = (j < HIMG);
  const bool jm1ok = (j - 1 >= 0) && (j - 1 < HIMG);
  const bool jp1ok = (j + 1 < HIMG);
  auto xsl = [&](int p) -> float {
    int ps = (p >= NROWS) ? p - NROWS : p;
    return xs_src[(size_t)ps * DIM + d];
  };
  float a0=0,b0=0,c0=0,a1=0,b1=0,c1=0,a2,b2,c2;
  auto load3 = [&](int r, float& A, float& B, float& C){
    A = 0.f; B = 0.f; C = 0.f;
    if (r >= 0 && r < HIMG){
      int base = r * HIMG;
      if (jm1ok) A = xsl(base + j - 1);
      if (jok)   B = xsl(base + j);
      if (jp1ok) C = xsl(base + j + 1);
    }
  };
  load3(i0 - 1, a0, b0, c0);
  load3(i0,     a1, b1, c1);
  __syncthreads();   // att staged

  float acc[8] = {};
  for (int ci = 0; ci < CI; ci++){
    int i = i0 + ci;
    load3(i + 1, a2, b2, c2);
    float xx = 0.f;
    if (i < HIMG && jok){
      xx = cb + b1
         + w9[0]*a0 + w9[1]*b0 + w9[2]*c0
         + w9[3]*a1 + w9[4]*b1 + w9[5]*c1
         + w9[6]*a2 + w9[7]*b2 + w9[8]*c2;
    }
    int pos = ci * TJ + jg;
    float4 p0 = *(const float4*)(smem + pos * 8);
    float4 p1 = *(const float4*)(smem + pos * 8 + 4);
    acc[0] += xx * p0.x; acc[1] += xx * p0.y;
    acc[2] += xx * p0.z; acc[3] += xx * p0.w;
    acc[4] += xx * p1.x; acc[5] += xx * p1.y;
    acc[6] += xx * p1.z; acc[7] += xx * p1.w;
    a0=a1; b0=b1; c0=c1; a1=a2; b1=b2; c1=c2;
  }
  // pair-reduce over jg within wave (lanes l <-> l^32 share dl)
  #pragma unroll
  for (int h = 0; h < 8; h++) acc[h] += __shfl_xor(acc[h], 32);
  __syncthreads();   // all waves done reading att before overlay
  int lane = t & 63, w = t >> 6;
  if (lane < 32){
    #pragma unroll
    for (int h = 0; h < 8; h++) smem[(w * 8 + h) * 32 + lane] = acc[h];
  }
  __syncthreads();
  if (t < 256){
    int h = t >> 5, d2 = t & 31;
    float s = 0.f;
    #pragma unroll
    for (int w2 = 0; w2 < 8; w2++) s += smem[(w2 * 8 + h) * 32 + d2];
    sblk[((size_t)(jt * NIT + it) * 8 + h) * DIM + dc * DCW + d2] = s;
  }
}

// ---------------- K7b: reduce sblk over 144 tiles -> sraw[h][d]
__global__ __launch_bounds__(64) void k7b(const float* __restrict__ sblk, float* __restrict__ sraw){
  int b = blockIdx.x;           // 64 = 8 h x 8 dq
  int h = b >> 3, dq = b & 7;
  int d = dq * 64 + threadIdx.x;
  float s = 0.f;
  for (int t2 = 0; t2 < NJT * NIT; t2++) s += sblk[((size_t)t2 * 8 + h) * DIM + d];
  sraw[h * DIM + d] = s;
}

// ---------------- K8a: O1[o] = qvec[o] + b_v[o] + sfin(h). w_v[:,o]
__global__ __launch_bounds__(256) void k8a(const float* __restrict__ sraw, const float* __restrict__ zpart,
                                           const float* __restrict__ attn, const float* __restrict__ cls,
                                           const float* __restrict__ qvec, const float* __restrict__ b_v,
                                           const float* __restrict__ w_v, float* __restrict__ O1){
  int b = blockIdx.x, t = threadIdx.x;
  int h = b >> 1;
  __shared__ float sf[512]; __shared__ float red[256];
  float Zh = 0.f;
  #pragma unroll
  for (int k = 0; k < 32; k++) Zh += zpart[h * 32 + k];
  float e0 = attn[(size_t)h * SPP];
  for (int k = t; k < 512; k += 256) sf[k] = (sraw[h * DIM + k] + e0 * cls[k]) / Zh;
  __syncthreads();
  int oo = t & 31, ks = t >> 5;
  int o = b * 32 + oo;
  float acc = 0.f;
  for (int kk = ks * 64; kk < ks * 64 + 64; kk++) acc += sf[kk] * w_v[(size_t)kk * DIM + o];
  red[t] = acc; __syncthreads();
  if (ks == 0){
    float s = red[oo];
    #pragma unroll
    for (int q2 = 1; q2 < 8; q2++) s += red[oo + 32 * q2];
    O1[o] = qvec[o] + b_v[o] + s;
  }
}

// ---------------- K8b: O2 = O1 + relu(O1@w_o + b_o)
__global__ __launch_bounds__(256) void k8b(const float* __restrict__ O1, const float* __restrict__ w_o,
                                           const float* __restrict__ b_o, float* __restrict__ O2){
  int b = blockIdx.x, t = threadIdx.x;
  __shared__ float sf[512]; __shared__ float red[256];
  for (int k = t; k < 512; k += 256) sf[k] = O1[k];
  __syncthreads();
  int oo = t & 31, ks = t >> 5;
  int o = b * 32 + oo;
  float acc = 0.f;
  for (int kk = ks * 64; kk < ks * 64 + 64; kk++) acc += sf[kk] * w_o[(size_t)kk * DIM + o];
  red[t] = acc; __syncthreads();
  if (ks == 0){
    float s = red[oo];
    #pragma unroll
    for (int q2 = 1; q2 < 8; q2++) s += red[oo + 32 * q2];
    float r = s + b_o[o];
    O2[o] = sf[o] + (r > 0.f ? r : 0.f);
  }
}

// ---------------- K8c: out = O2@w_fc + b_fc (2 logits)
__global__ __launch_bounds__(256) void k8c(const float* __restrict__ O2, const float* __restrict__ w_fc,
                                           const float* __restrict__ b_fc, float* __restrict__ out){
  int t = threadIdx.x;
  __shared__ float r0[256], r1[256];
  float a0 = 0.f, a1 = 0.f;
  for (int k = t; k < 512; k += 256){
    float v = O2[k];
    a0 += v * w_fc[2 * k];
    a1 += v * w_fc[2 * k + 1];
  }
  r0[t] = a0; r1[t] = a1; __syncthreads();
  for (int s = 128; s; s >>= 1){ if (t < s){ r0[t] += r0[t+s]; r1[t] += r1[t+s]; } __syncthreads(); }
  if (t == 0){ out[0] = r0[0] + b_fc[0]; out[1] = r1[0] + b_fc[1]; }
}

extern "C" void kernel_launch(void* const* d_in, const int* in_sizes, int n_in,
                              void* d_out, int out_size, void* d_ws, size_t ws_size,
                              hipStream_t stream) {
  const float* in     = (const float*)d_in[0];
  const float* w_enc  = (const float*)d_in[1];
  const float* b_enc  = (const float*)d_in[2];
  const float* cls    = (const float*)d_in[3];
  const float* conv_w = (const float*)d_in[4];
  const float* conv_b = (const float*)d_in[5];
  const float* w_q    = (const float*)d_in[6];
  const float* b_q    = (const float*)d_in[7];
  const float* w_k    = (const float*)d_in[8];
  const float* b_k    = (const float*)d_in[9];
  const float* w_v    = (const float*)d_in[10];
  const float* b_v    = (const float*)d_in[11];
  const float* w_o    = (const float*)d_in[12];
  const float* b_o    = (const float*)d_in[13];
  const float* w_fc   = (const float*)d_in[14];
  const float* b_fc   = (const float*)d_in[15];

  float* out    = (float*)d_out;
  float* xs_out = out + 2;                      // i_shift (1,60000,512)
  float* A1     = out + 2 + (size_t)NROWS * DIM;
  float* ws     = (float*)d_ws;

  k1 <<<NB1, 256, 0, stream>>>(in, w_enc, b_enc, A1, ws + OFF_PMAX, (int*)(ws + OFF_PIDX));
  k4a<<<16, 256, 0, stream>>>(in, ws + OFF_PMAX, (const int*)(ws + OFF_PIDX), w_q, b_q,
                              ws + OFF_QVEC, ws + OFF_QROW);
  k4b<<<16, 256, 0, stream>>>(w_k, ws + OFF_QVEC, ws + OFF_U);
  k4c<<<1, 512, 0, stream>>>(b_k, ws + OFF_QVEC, cls, ws + OFF_U, ws + OFF_S0);
  k5 <<<NBLK, 512, 0, stream>>>(in, ws + OFF_QROW, conv_w, conv_b, ws + OFF_U,
                                xs_out, ws + OFF_SPART);
  k6a<<<256, 256, 0, stream>>>(ws + OFF_SPART, ws + OFF_S0, ws + OFF_SCOMB, ws + OFF_MAXP);
  k6c<<<256, 256, 0, stream>>>(ws + OFF_SCOMB, ws + OFF_MAXP, ws + OFF_ATTN, ws + OFF_ZP);
  k7 <<<NBLK, 512, 0, stream>>>(xs_out, conv_w, conv_b, ws + OFF_ATTN, ws + OFF_SBLK);
  k7b<<<64, 64, 0, stream>>>(ws + OFF_SBLK, ws + OFF_SRAW);
  k8a<<<16, 256, 0, stream>>>(ws + OFF_SRAW, ws + OFF_ZP, ws + OFF_ATTN, cls,
                              ws + OFF_QVEC, b_v, w_v, ws + OFF_O1);
  k8b<<<16, 256, 0, stream>>>(ws + OFF_O1, w_o, b_o, ws + OFF_O2);
  k8c<<<1, 256, 0, stream>>>(ws + OFF_O2, w_fc, b_fc, out);
}

// Round 4
// 482.563 us; speedup vs baseline: 1.3838x; 1.2584x over previous
//
#include <hip/hip_runtime.h>
#include <math.h>

// Problem constants
#define NROWS   60000
#define DIM     512
#define HIMG    245          // ceil(sqrt(60000)); 245*245 = 60025
#define P2      60025
#define SP      60026        // cls + 60025 positions
#define SPP     60032        // padded
#define RSCALE  0.04419417382415922f  // 1/sqrt(512)

// K5/K7 tiling: block = 28 i x 16 j x 32 d, 256 threads = 16 jg x 16 dq (2 d each)
#define CI    28
#define TJ    16
#define DCW   32
#define NJT   16             // ceil(245/16)
#define NIT   9              // ceil(245/28)
#define NDC   16             // 512/32
#define NBLK  (NJT*NIT*NDC)  // 2304

// K1 grid
#define NB1   2048
#define RPB   30

// ws layout (float offsets)
#define OFF_PMAX  0
#define OFF_PIDX  2048
#define OFF_QROW  4096
#define OFF_QVEC  4608
#define OFF_U     5120
#define OFF_S0    9216
#define OFF_MAXP  9280
#define OFF_ZP    9536
#define OFF_SRAW  9792
#define OFF_O1    13888
#define OFF_O2    14400
#define OFF_SPART 16384                      // 16*8*60032
#define OFF_SCOMB (OFF_SPART + 7684096)
#define OFF_ATTN  (OFF_SCOMB + 480256)
#define OFF_SBLK  (OFF_ATTN + 480256)        // 144*8*512

// ---------------- K1
__global__ __launch_bounds__(256) void k1(const float* __restrict__ in,
                                          const float* __restrict__ w_enc,
                                          const float* __restrict__ b_enc,
                                          float* __restrict__ A1,
                                          float* __restrict__ pmax, int* __restrict__ pidx){
  int b = blockIdx.x;
  int w = threadIdx.x >> 6, l = threadIdx.x & 63;
  float4 we0 = ((const float4*)w_enc)[l];
  float4 we1 = ((const float4*)w_enc)[64 + l];
  float be = b_enc[0];
  int r0 = b * RPB;
  float bm = -3.0e38f; int bi = 0;
  for (int k = w; k < RPB; k += 4){
    int r = r0 + k;
    if (r < NROWS){
      const float4* rp = (const float4*)(in + (size_t)r * DIM);
      float4 x0 = rp[l], x1 = rp[64 + l];
      float s = x0.x*we0.x + x0.y*we0.y + x0.z*we0.z + x0.w*we0.w
              + x1.x*we1.x + x1.y*we1.y + x1.z*we1.z + x1.w*we1.w;
      #pragma unroll
      for (int d = 32; d; d >>= 1) s += __shfl_xor(s, d);
      if (l == 0){
        float z = s + be;
        A1[r] = 1.f / (1.f + __expf(-z));
        if (z > bm){ bm = z; bi = r; }
      }
    }
  }
  __shared__ float sm[4]; __shared__ int si[4];
  if (l == 0){ sm[w] = bm; si[w] = bi; }
  __syncthreads();
  if (threadIdx.x == 0){
    float m = sm[0]; int i = si[0];
    for (int t2 = 1; t2 < 4; t2++){
      if (sm[t2] > m || (sm[t2] == m && si[t2] < i)){ m = sm[t2]; i = si[t2]; }
    }
    pmax[b] = m; pidx[b] = i;
  }
}

// ---------------- K4a
__global__ __launch_bounds__(256) void k4a(const float* __restrict__ in,
                                           const float* __restrict__ pmax, const int* __restrict__ pidx,
                                           const float* __restrict__ w_q, const float* __restrict__ b_q,
                                           float* __restrict__ qvec, float* __restrict__ qrow){
  __shared__ float qs[512];
  __shared__ float rm[256]; __shared__ int ri[256];
  __shared__ float red[256];
  int t = threadIdx.x;
  float m = -3.0e38f; int mi = 0;
  for (int k = t; k < NB1; k += 256){
    float v = pmax[k]; int id = pidx[k];
    if (v > m || (v == m && id < mi)){ m = v; mi = id; }
  }
  rm[t] = m; ri[t] = mi; __syncthreads();
  for (int s = 128; s; s >>= 1){
    if (t < s){
      if (rm[t+s] > rm[t] || (rm[t+s] == rm[t] && ri[t+s] < ri[t])){ rm[t] = rm[t+s]; ri[t] = ri[t+s]; }
    }
    __syncthreads();
  }
  int idx = ri[0];
  for (int k = t; k < 512; k += 256){
    float v = in[(size_t)idx * DIM + k];
    qs[k] = v;
    qrow[k] = v;
  }
  __syncthreads();
  int b = blockIdx.x;
  int oo = t & 31, ks = t >> 5;
  int o = b * 32 + oo;
  float acc = 0.f;
  for (int kk = ks * 64; kk < ks * 64 + 64; kk++) acc += qs[kk] * w_q[(size_t)kk * DIM + o];
  red[t] = acc; __syncthreads();
  if (ks == 0){
    float s = red[oo];
    #pragma unroll
    for (int q2 = 1; q2 < 8; q2++) s += red[oo + 32 * q2];
    qvec[o] = s + b_q[o];
  }
}

// ---------------- K4b
__global__ __launch_bounds__(256) void k4b(const float* __restrict__ w_k,
                                           const float* __restrict__ qvec, float* __restrict__ u){
  __shared__ float qs[512];
  int t = threadIdx.x;
  for (int k = t; k < 512; k += 256) qs[k] = qvec[k];
  __syncthreads();
  int b = blockIdx.x;
  int dd = t >> 3, h = t & 7;
  int d = b * 32 + dd;
  const float4* wr = (const float4*)(w_k + (size_t)d * DIM + h * 64);
  float acc = 0.f;
  #pragma unroll
  for (int k = 0; k < 16; k++){
    float4 v = wr[k];
    int base = h * 64 + 4 * k;
    acc += v.x * qs[base] + v.y * qs[base+1] + v.z * qs[base+2] + v.w * qs[base+3];
  }
  u[(size_t)d * 8 + h] = acc * RSCALE;
}

// ---------------- K4c
__global__ __launch_bounds__(512) void k4c(const float* __restrict__ b_k, const float* __restrict__ qvec,
                                           const float* __restrict__ cls, const float* __restrict__ u,
                                           float* __restrict__ scores0){
  int t = threadIdx.x; int w = t >> 6, l = t & 63;
  float c = b_k[t] * qvec[t];
  #pragma unroll
  for (int d = 32; d; d >>= 1) c += __shfl_xor(c, d);
  float cs = 0.f;
  #pragma unroll
  for (int m = 0; m < 8; m++){
    int d = l + m * 64;
    cs += cls[d] * u[(size_t)d * 8 + w];
  }
  #pragma unroll
  for (int d = 32; d; d >>= 1) cs += __shfl_xor(cs, d);
  if (l == 0) scores0[w] = cs + c * RSCALE;
}

// ---------------- K5: pipelined conv + in-register scores, no main-loop barriers
__global__ __launch_bounds__(256, 4) void k5(const float* __restrict__ in,
                                          const float* __restrict__ qrow,
                                          const float* __restrict__ conv_w, const float* __restrict__ conv_b,
                                          const float* __restrict__ u,
                                          float* __restrict__ xs_out, float* __restrict__ spart){
  int bid = blockIdx.x;
  int sw = (bid & 7) * (NBLK >> 3) + (bid >> 3);
  int dc = sw & 15; int r2 = sw >> 4;
  int jt = r2 / NIT, it = r2 % NIT;
  int i0 = it * CI, j0 = jt * TJ;
  int t = threadIdx.x;
  int dq = t & 15, jg = t >> 4;          // 16 jg x 16 dq
  int d = dc * DCW + dq * 2;
  int j = j0 + jg;

  __shared__ float sL[CI * TJ * 9];      // 4032 floats, pad-9 stride

  // u[d..d+1][0..7] -> 16 regs
  float uhx[8], uhy[8];
  {
    const float4* up = (const float4*)(u + (size_t)d * 8);
    float4 a = up[0], b = up[1], c2 = up[2], e = up[3];
    uhx[0]=a.x; uhx[1]=a.y; uhx[2]=a.z; uhx[3]=a.w;
    uhx[4]=b.x; uhx[5]=b.y; uhx[6]=b.z; uhx[7]=b.w;
    uhy[0]=c2.x; uhy[1]=c2.y; uhy[2]=c2.z; uhy[3]=c2.w;
    uhy[4]=e.x; uhy[5]=e.y; uhy[6]=e.z; uhy[7]=e.w;
  }
  float wx[9], wy[9];
  #pragma unroll
  for (int k = 0; k < 9; k++){ wx[k] = conv_w[(size_t)d*9+k]; wy[k] = conv_w[(size_t)(d+1)*9+k]; }
  float cbx = conv_b[d], cby = conv_b[d+1];
  float2 Qd = *(const float2*)(qrow + d);

  const bool jok   = (j < HIMG);
  const bool jm1ok = (j >= 1) && (j - 1 < HIMG);
  const bool jp1ok = (j + 1 < HIMG);

  // raw loads; invalid -> Qd so relu(x-Qd)=0 reproduces SAME zero-padding after relu
  auto loadraw = [&](int rr, float2& A, float2& B, float2& C){
    A = Qd; B = Qd; C = Qd;
    if (rr >= 0 && rr < HIMG){
      int base = rr * HIMG;
      if (jm1ok){ int p = base + j - 1; if (p >= NROWS) p -= NROWS; A = *(const float2*)(in + (size_t)p*DIM + d); }
      if (jok)  { int p = base + j;     if (p >= NROWS) p -= NROWS; B = *(const float2*)(in + (size_t)p*DIM + d); }
      if (jp1ok){ int p = base + j + 1; if (p >= NROWS) p -= NROWS; C = *(const float2*)(in + (size_t)p*DIM + d); }
    }
  };

  float2 cA, cB, cC, nA, nB, nC;
  float t0m2x=0,t0m2y=0, t0m1x=0,t0m1y=0, t1m1x=0,t1m1y=0, bm1x=0,bm1y=0;
  loadraw(i0 - 1, cA, cB, cC);

  for (int rr = i0 - 1; rr <= i0 + CI; rr++){
    if (rr < i0 + CI) loadraw(rr + 1, nA, nB, nC);   // prefetch next row

    // xs values of row rr
    float ax = fmaxf(cA.x - Qd.x, 0.f), ay = fmaxf(cA.y - Qd.y, 0.f);
    float bx = fmaxf(cB.x - Qd.x, 0.f), by = fmaxf(cB.y - Qd.y, 0.f);
    float cx = fmaxf(cC.x - Qd.x, 0.f), cy = fmaxf(cC.y - Qd.y, 0.f);

    if (rr >= i0 && rr < i0 + CI && rr < HIMG && jok){
      int p = rr * HIMG + j;
      if (p < NROWS){ float2 v = make_float2(bx, by); *(float2*)(xs_out + (size_t)p*DIM + d) = v; }
    }

    float T0x = wx[0]*ax + wx[1]*bx + wx[2]*cx,  T0y = wy[0]*ay + wy[1]*by + wy[2]*cy;
    float T1x = wx[3]*ax + wx[4]*bx + wx[5]*cx,  T1y = wy[3]*ay + wy[4]*by + wy[5]*cy;
    float T2x = wx[6]*ax + wx[7]*bx + wx[8]*cx,  T2y = wy[6]*ay + wy[7]*by + wy[8]*cy;

    if (rr >= i0 + 1){
      int i = rr - 1;
      float xxx = 0.f, xxy = 0.f;
      if (i < HIMG && jok){
        xxx = cbx + bm1x + t0m2x + t1m1x + T2x;
        xxy = cby + bm1y + t0m2y + t1m1y + T2y;
      }
      float s[8];
      #pragma unroll
      for (int h = 0; h < 8; h++) s[h] = xxx * uhx[h] + xxy * uhy[h];
      // packed butterfly over 16 dq lanes -> lane dq holds full sum of s[dq&7]
      float t4[4];
      #pragma unroll
      for (int k2 = 0; k2 < 4; k2++){
        float keep = (dq & 1) ? s[2*k2+1] : s[2*k2];
        float send = (dq & 1) ? s[2*k2]   : s[2*k2+1];
        t4[k2] = keep + __shfl_xor(send, 1);
      }
      float t2a[2];
      #pragma unroll
      for (int k2 = 0; k2 < 2; k2++){
        float keep = (dq & 2) ? t4[2*k2+1] : t4[2*k2];
        float send = (dq & 2) ? t4[2*k2]   : t4[2*k2+1];
        t2a[k2] = keep + __shfl_xor(send, 2);
      }
      float keep = (dq & 4) ? t2a[1] : t2a[0];
      float send = (dq & 4) ? t2a[0] : t2a[1];
      float v = keep + __shfl_xor(send, 4);
      v += __shfl_xor(v, 8);
      if (dq < 8) sL[((i - i0) * TJ + jg) * 9 + dq] = v;
    }
    t0m2x = t0m1x; t0m2y = t0m1y;
    t0m1x = T0x;   t0m1y = T0y;
    t1m1x = T1x;   t1m1y = T1y;
    bm1x  = bx;    bm1y  = by;
    cA = nA; cB = nB; cC = nC;
  }
  __syncthreads();
  // flush scores coalesced
  for (int f = t; f < CI * TJ * 8; f += 256){
    int h = f / (CI * TJ);
    int p = f - h * (CI * TJ);
    int iL = p >> 4, jg2 = p & 15;
    int i = i0 + iL, jj = j0 + jg2;
    if (i < HIMG && jj < HIMG)
      spart[((size_t)(dc * 8 + h)) * SPP + i * HIMG + jj + 1] = sL[p * 9 + h];
  }
}

// ---------------- K6a
__global__ __launch_bounds__(256) void k6a(const float* __restrict__ spart, const float* __restrict__ scores0,
                                           float* __restrict__ scomb, float* __restrict__ maxpart){
  int b = blockIdx.x, t = threadIdx.x;
  int h = b >> 5, sl = b & 31;
  int sp0 = sl * 1876, sp1 = min(sp0 + 1876, SP);
  float m = -3.0e38f;
  for (int sp = sp0 + t; sp < sp1; sp += 256){
    float v;
    if (sp == 0) v = scores0[h];
    else {
      v = 0.f;
      #pragma unroll
      for (int dcc = 0; dcc < NDC; dcc++) v += spart[((size_t)(dcc * 8 + h)) * SPP + sp];
    }
    scomb[(size_t)h * SPP + sp] = v;
    m = fmaxf(m, v);
  }
  __shared__ float red[256];
  red[t] = m; __syncthreads();
  for (int s = 128; s; s >>= 1){ if (t < s) red[t] = fmaxf(red[t], red[t+s]); __syncthreads(); }
  if (t == 0) maxpart[h * 32 + sl] = red[0];
}

// ---------------- K6c
__global__ __launch_bounds__(256) void k6c(const float* __restrict__ scomb, const float* __restrict__ maxpart,
                                           float* __restrict__ attn, float* __restrict__ zpart){
  int b = blockIdx.x, t = threadIdx.x;
  int h = b >> 5, sl = b & 31;
  float m = -3.0e38f;
  #pragma unroll
  for (int k = 0; k < 32; k++) m = fmaxf(m, maxpart[h * 32 + k]);
  int sp0 = sl * 1876, sp1 = min(sp0 + 1876, SP);
  float z = 0.f;
  for (int sp = sp0 + t; sp < sp1; sp += 256){
    float e = __expf(scomb[(size_t)h * SPP + sp] - m);
    attn[(size_t)h * SPP + sp] = e;
    z += e;
  }
  __shared__ float red[256];
  red[t] = z; __syncthreads();
  for (int s = 128; s; s >>= 1){ if (t < s) red[t] += red[t+s]; __syncthreads(); }
  if (t == 0) zpart[h * 32 + sl] = red[0];
}

// ---------------- K7: pipelined conv + register-accumulated weighted sums
__global__ __launch_bounds__(256, 4) void k7(const float* __restrict__ xs_src,
                                          const float* __restrict__ conv_w, const float* __restrict__ conv_b,
                                          const float* __restrict__ attn, float* __restrict__ sblk){
  int bid = blockIdx.x;
  int sw = (bid & 7) * (NBLK >> 3) + (bid >> 3);
  int dc = sw & 15; int r2 = sw >> 4;
  int jt = r2 / NIT, it = r2 % NIT;
  int i0 = it * CI, j0 = jt * TJ;
  int t = threadIdx.x;
  int dq = t & 15, jg = t >> 4;
  int d = dc * DCW + dq * 2;
  int j = j0 + jg;

  __shared__ float smem[CI * TJ * 9];   // attL [pos][h] pad-9; overlaid by wred (1024) at end

  // stage attn tile: [pos*9 + h]
  #pragma unroll
  for (int h = 0; h < 8; h++){
    for (int p = t; p < CI * TJ; p += 256){
      int iL = p >> 4, jg2 = p & 15;
      int i = i0 + iL, jj = j0 + jg2;
      smem[p * 9 + h] = (i < HIMG && jj < HIMG) ? attn[(size_t)h * SPP + i * HIMG + jj + 1] : 0.f;
    }
  }

  float wx[9], wy[9];
  #pragma unroll
  for (int k = 0; k < 9; k++){ wx[k] = conv_w[(size_t)d*9+k]; wy[k] = conv_w[(size_t)(d+1)*9+k]; }
  float cbx = conv_b[d], cby = conv_b[d+1];

  const bool jok   = (j < HIMG);
  const bool jm1ok = (j >= 1) && (j - 1 < HIMG);
  const bool jp1ok = (j + 1 < HIMG);

  auto loadraw = [&](int rr, float2& A, float2& B, float2& C){
    A = make_float2(0.f,0.f); B = A; C = A;
    if (rr >= 0 && rr < HIMG){
      int base = rr * HIMG;
      if (jm1ok){ int p = base + j - 1; if (p >= NROWS) p -= NROWS; A = *(const float2*)(xs_src + (size_t)p*DIM + d); }
      if (jok)  { int p = base + j;     if (p >= NROWS) p -= NROWS; B = *(const float2*)(xs_src + (size_t)p*DIM + d); }
      if (jp1ok){ int p = base + j + 1; if (p >= NROWS) p -= NROWS; C = *(const float2*)(xs_src + (size_t)p*DIM + d); }
    }
  };

  float2 cA, cB, cC, nA, nB, nC;
  float t0m2x=0,t0m2y=0, t0m1x=0,t0m1y=0, t1m1x=0,t1m1y=0, bm1x=0,bm1y=0;
  float accx[8] = {}, accy[8] = {};
  loadraw(i0 - 1, cA, cB, cC);
  __syncthreads();   // attL staged

  for (int rr = i0 - 1; rr <= i0 + CI; rr++){
    if (rr < i0 + CI) loadraw(rr + 1, nA, nB, nC);

    float T0x = wx[0]*cA.x + wx[1]*cB.x + wx[2]*cC.x,  T0y = wy[0]*cA.y + wy[1]*cB.y + wy[2]*cC.y;
    float T1x = wx[3]*cA.x + wx[4]*cB.x + wx[5]*cC.x,  T1y = wy[3]*cA.y + wy[4]*cB.y + wy[5]*cC.y;
    float T2x = wx[6]*cA.x + wx[7]*cB.x + wx[8]*cC.x,  T2y = wy[6]*cA.y + wy[7]*cB.y + wy[8]*cC.y;

    if (rr >= i0 + 1){
      int i = rr - 1;
      if (i < HIMG && jok){
        float xxx = cbx + bm1x + t0m2x + t1m1x + T2x;
        float xxy = cby + bm1y + t0m2y + t1m1y + T2y;
        int pL = (i - i0) * TJ + jg;
        #pragma unroll
        for (int h = 0; h < 8; h++){
          float av = smem[pL * 9 + h];
          accx[h] += xxx * av; accy[h] += xxy * av;
        }
      }
    }
    t0m2x = t0m1x; t0m2y = t0m1y;
    t0m1x = T0x;   t0m1y = T0y;
    t1m1x = T1x;   t1m1y = T1y;
    bm1x  = cB.x;  bm1y  = cB.y;
    cA = nA; cB = nB; cC = nC;
  }

  // reduce over jg: in-wave (jg bits are lane bits 4-5)
  #pragma unroll
  for (int o = 16; o <= 32; o <<= 1){
    #pragma unroll
    for (int h = 0; h < 8; h++){
      accx[h] += __shfl_xor(accx[h], o);
      accy[h] += __shfl_xor(accy[h], o);
    }
  }
  __syncthreads();   // done reading attL
  float* wred = smem; // [w][dq][h*2+dd] : 4*16*16 = 1024
  int lane = t & 63, w = t >> 6;
  if (lane < 16){
    #pragma unroll
    for (int h = 0; h < 8; h++){
      wred[(w * 16 + dq) * 16 + h * 2]     = accx[h];
      wred[(w * 16 + dq) * 16 + h * 2 + 1] = accy[h];
    }
  }
  __syncthreads();
  {
    int h = t >> 5, dl = t & 31;
    int dq2 = dl >> 1, dd = dl & 1;
    float s = 0.f;
    #pragma unroll
    for (int w2 = 0; w2 < 4; w2++) s += wred[(w2 * 16 + dq2) * 16 + h * 2 + dd];
    sblk[((size_t)(jt * NIT + it) * 8 + h) * DIM + dc * DCW + dl] = s;
  }
}

// ---------------- K7b
__global__ __launch_bounds__(64) void k7b(const float* __restrict__ sblk, float* __restrict__ sraw){
  int b = blockIdx.x;
  int h = b >> 3, dq = b & 7;
  int d = dq * 64 + threadIdx.x;
  float s = 0.f;
  for (int t2 = 0; t2 < NJT * NIT; t2++) s += sblk[((size_t)t2 * 8 + h) * DIM + d];
  sraw[h * DIM + d] = s;
}

// ---------------- K8a
__global__ __launch_bounds__(256) void k8a(const float* __restrict__ sraw, const float* __restrict__ zpart,
                                           const float* __restrict__ attn, const float* __restrict__ cls,
                                           const float* __restrict__ qvec, const float* __restrict__ b_v,
                                           const float* __restrict__ w_v, float* __restrict__ O1){
  int b = blockIdx.x, t = threadIdx.x;
  int h = b >> 1;
  __shared__ float sf[512]; __shared__ float red[256];
  float Zh = 0.f;
  #pragma unroll
  for (int k = 0; k < 32; k++) Zh += zpart[h * 32 + k];
  float e0 = attn[(size_t)h * SPP];
  for (int k = t; k < 512; k += 256) sf[k] = (sraw[h * DIM + k] + e0 * cls[k]) / Zh;
  __syncthreads();
  int oo = t & 31, ks = t >> 5;
  int o = b * 32 + oo;
  float acc = 0.f;
  for (int kk = ks * 64; kk < ks * 64 + 64; kk++) acc += sf[kk] * w_v[(size_t)kk * DIM + o];
  red[t] = acc; __syncthreads();
  if (ks == 0){
    float s = red[oo];
    #pragma unroll
    for (int q2 = 1; q2 < 8; q2++) s += red[oo + 32 * q2];
    O1[o] = qvec[o] + b_v[o] + s;
  }
}

// ---------------- K8b
__global__ __launch_bounds__(256) void k8b(const float* __restrict__ O1, const float* __restrict__ w_o,
                                           const float* __restrict__ b_o, float* __restrict__ O2){
  int b = blockIdx.x, t = threadIdx.x;
  __shared__ float sf[512]; __shared__ float red[256];
  for (int k = t; k < 512; k += 256) sf[k] = O1[k];
  __syncthreads();
  int oo = t & 31, ks = t >> 5;
  int o = b * 32 + oo;
  float acc = 0.f;
  for (int kk = ks * 64; kk < ks * 64 + 64; kk++) acc += sf[kk] * w_o[(size_t)kk * DIM + o];
  red[t] = acc; __syncthreads();
  if (ks == 0){
    float s = red[oo];
    #pragma unroll
    for (int q2 = 1; q2 < 8; q2++) s += red[oo + 32 * q2];
    float r = s + b_o[o];
    O2[o] = sf[o] + (r > 0.f ? r : 0.f);
  }
}

// ---------------- K8c
__global__ __launch_bounds__(256) void k8c(const float* __restrict__ O2, const float* __restrict__ w_fc,
                                           const float* __restrict__ b_fc, float* __restrict__ out){
  int t = threadIdx.x;
  __shared__ float r0[256], r1[256];
  float a0 = 0.f, a1 = 0.f;
  for (int k = t; k < 512; k += 256){
    float v = O2[k];
    a0 += v * w_fc[2 * k];
    a1 += v * w_fc[2 * k + 1];
  }
  r0[t] = a0; r1[t] = a1; __syncthreads();
  for (int s = 128; s; s >>= 1){ if (t < s){ r0[t] += r0[t+s]; r1[t] += r1[t+s]; } __syncthreads(); }
  if (t == 0){ out[0] = r0[0] + b_fc[0]; out[1] = r1[0] + b_fc[1]; }
}

extern "C" void kernel_launch(void* const* d_in, const int* in_sizes, int n_in,
                              void* d_out, int out_size, void* d_ws, size_t ws_size,
                              hipStream_t stream) {
  const float* in     = (const float*)d_in[0];
  const float* w_enc  = (const float*)d_in[1];
  const float* b_enc  = (const float*)d_in[2];
  const float* cls    = (const float*)d_in[3];
  const float* conv_w = (const float*)d_in[4];
  const float* conv_b = (const float*)d_in[5];
  const float* w_q    = (const float*)d_in[6];
  const float* b_q    = (const float*)d_in[7];
  const float* w_k    = (const float*)d_in[8];
  const float* b_k    = (const float*)d_in[9];
  const float* w_v    = (const float*)d_in[10];
  const float* b_v    = (const float*)d_in[11];
  const float* w_o    = (const float*)d_in[12];
  const float* b_o    = (const float*)d_in[13];
  const float* w_fc   = (const float*)d_in[14];
  const float* b_fc   = (const float*)d_in[15];

  float* out    = (float*)d_out;
  float* xs_out = out + 2;
  float* A1     = out + 2 + (size_t)NROWS * DIM;
  float* ws     = (float*)d_ws;

  k1 <<<NB1, 256, 0, stream>>>(in, w_enc, b_enc, A1, ws + OFF_PMAX, (int*)(ws + OFF_PIDX));
  k4a<<<16, 256, 0, stream>>>(in, ws + OFF_PMAX, (const int*)(ws + OFF_PIDX), w_q, b_q,
                              ws + OFF_QVEC, ws + OFF_QROW);
  k4b<<<16, 256, 0, stream>>>(w_k, ws + OFF_QVEC, ws + OFF_U);
  k4c<<<1, 512, 0, stream>>>(b_k, ws + OFF_QVEC, cls, ws + OFF_U, ws + OFF_S0);
  k5 <<<NBLK, 256, 0, stream>>>(in, ws + OFF_QROW, conv_w, conv_b, ws + OFF_U,
                                xs_out, ws + OFF_SPART);
  k6a<<<256, 256, 0, stream>>>(ws + OFF_SPART, ws + OFF_S0, ws + OFF_SCOMB, ws + OFF_MAXP);
  k6c<<<256, 256, 0, stream>>>(ws + OFF_SCOMB, ws + OFF_MAXP, ws + OFF_ATTN, ws + OFF_ZP);
  k7 <<<NBLK, 256, 0, stream>>>(xs_out, conv_w, conv_b, ws + OFF_ATTN, ws + OFF_SBLK);
  k7b<<<64, 64, 0, stream>>>(ws + OFF_SBLK, ws + OFF_SRAW);
  k8a<<<16, 256, 0, stream>>>(ws + OFF_SRAW, ws + OFF_ZP, ws + OFF_ATTN, cls,
                              ws + OFF_QVEC, b_v, w_v, ws + OFF_O1);
  k8b<<<16, 256, 0, stream>>>(ws + OFF_O1, w_o, b_o, ws + OFF_O2);
  k8c<<<1, 256, 0, stream>>>(ws + OFF_O2, w_fc, b_fc, out);
}